// Round 1
// baseline (737.442 us; speedup 1.0000x reference)
//
#include <hip/hip_runtime.h>

// Deformable Conv2D: B=8, CIN=COUT=256, H=W=64, K=3, stride=1, pad=1, + ReLU
// out[b,o,ho,wo] = relu( sum_{c,k} w[o,c,k] * bilinear(x[b,c], p(b,k,ho,wo)) )
//
// Round 0: correct fused f32 VALU kernel.
// Block = (b, ho): computes all 256 outputs x 64 pixels of one row.
//  - prep: 9 taps x 64 pixels -> 4 clamped indices + 4 bilinear weights (LDS)
//  - loop c: stage v[9][64] (bilinear samples) + wslice[9][256] in LDS,
//            each thread FMAs a 16(o) x 4(s) register tile over 9 taps.

#define B_    8
#define CIN_  256
#define COUT_ 256
#define H_    64
#define W_    64
#define K2_   9
#define HW_   (H_ * W_)

__global__ __launch_bounds__(256) void deform_conv_relu_kernel(
    const float* __restrict__ x,       // [B, CIN, H, W]
    const float* __restrict__ offset,  // [B, 18, H, W]
    const float* __restrict__ weight,  // [COUT, CIN, 9]
    float* __restrict__ out)           // [B, COUT, H, W]
{
    const int ho  = blockIdx.x;   // output row
    const int b   = blockIdx.y;   // batch
    const int tid = threadIdx.x;  // 0..255

    __shared__ int   pidx[K2_][W_][4];   // 4 gather indices per (tap, pixel)
    __shared__ float pw  [K2_][W_][4];   // 4 bilinear weights (0 if invalid)
    __shared__ float vtile[K2_][W_];     // sampled values for current c
    __shared__ float wslice[K2_][COUT_]; // w[o][c][k] transposed to [k][o]

    // ---- prep: sampling geometry for this (b, ho), shared across channels ----
    for (int e = tid; e < K2_ * W_; e += 256) {
        const int k  = e >> 6;
        const int wo = e & 63;
        const float offy = offset[(((b * 18 + 2 * k    ) * H_) + ho) * W_ + wo];
        const float offx = offset[(((b * 18 + 2 * k + 1) * H_) + ho) * W_ + wo];
        const float py = (float)(k / 3 + ho - 1) + offy;
        const float px = (float)(k % 3 + wo - 1) + offx;
        const float y0f = floorf(py);
        const float x0f = floorf(px);
        const int   y0 = (int)y0f;
        const int   x0 = (int)x0f;
        const float fy = py - y0f;
        const float fx = px - x0f;
        const float wy[2] = {1.f - fy, fy};
        const float wx[2] = {1.f - fx, fx};
        const int   ys[2] = {y0, y0 + 1};
        const int   xs[2] = {x0, x0 + 1};
#pragma unroll
        for (int dy = 0; dy < 2; ++dy) {
#pragma unroll
            for (int dx = 0; dx < 2; ++dx) {
                const int yy = ys[dy], xx = xs[dx];
                const bool valid = (yy >= 0) && (yy < H_) && (xx >= 0) && (xx < W_);
                pidx[k][wo][dy * 2 + dx] = valid ? (yy * W_ + xx) : 0;
                pw  [k][wo][dy * 2 + dx] = valid ? (wy[dy] * wx[dx]) : 0.f;
            }
        }
    }

    float acc[16][4];
#pragma unroll
    for (int i = 0; i < 16; ++i)
#pragma unroll
        for (int j = 0; j < 4; ++j) acc[i][j] = 0.f;

    const int o_base = (tid >> 4) * 16;  // 16 output channels per thread
    const int s_base = (tid & 15) * 4;   // 4 pixels per thread

    const float* wthread = weight + (size_t)tid * (CIN_ * K2_);  // row o = tid

    for (int c = 0; c < CIN_; ++c) {
        __syncthreads();  // previous iter's LDS reads done (1st iter: prep done)

        // stage bilinear samples for channel c
        const float* xb = x + ((size_t)(b * CIN_ + c)) * HW_;
        for (int e = tid; e < K2_ * W_; e += 256) {
            const int k  = e >> 6;
            const int wo = e & 63;
            const int*   pi  = pidx[k][wo];
            const float* pww = pw[k][wo];
            vtile[k][wo] = pww[0] * xb[pi[0]] + pww[1] * xb[pi[1]]
                         + pww[2] * xb[pi[2]] + pww[3] * xb[pi[3]];
        }

        // stage weight slice: thread tid owns output channel o=tid
        {
            const float* wp = wthread + c * K2_;
#pragma unroll
            for (int k = 0; k < K2_; ++k) wslice[k][tid] = wp[k];
        }

        __syncthreads();

        // register-tile FMA: 16 o x 4 s x 9 k
#pragma unroll
        for (int k = 0; k < K2_; ++k) {
            const float4 v4 = *reinterpret_cast<const float4*>(&vtile[k][s_base]);
            const float va[4] = {v4.x, v4.y, v4.z, v4.w};
#pragma unroll
            for (int og = 0; og < 4; ++og) {
                const float4 w4 =
                    *reinterpret_cast<const float4*>(&wslice[k][o_base + og * 4]);
                const float wa[4] = {w4.x, w4.y, w4.z, w4.w};
#pragma unroll
                for (int jo = 0; jo < 4; ++jo)
#pragma unroll
                    for (int si = 0; si < 4; ++si)
                        acc[og * 4 + jo][si] += wa[jo] * va[si];
            }
        }
    }

    // ---- epilogue: ReLU + coalesced float4 stores ----
#pragma unroll
    for (int ol = 0; ol < 16; ++ol) {
        const int o = o_base + ol;
        float4 r;
        r.x = fmaxf(acc[ol][0], 0.f);
        r.y = fmaxf(acc[ol][1], 0.f);
        r.z = fmaxf(acc[ol][2], 0.f);
        r.w = fmaxf(acc[ol][3], 0.f);
        *reinterpret_cast<float4*>(
            &out[(((size_t)(b * COUT_ + o)) * H_ + ho) * W_ + s_base]) = r;
    }
}

extern "C" void kernel_launch(void* const* d_in, const int* in_sizes, int n_in,
                              void* d_out, int out_size, void* d_ws, size_t ws_size,
                              hipStream_t stream) {
    const float* x      = (const float*)d_in[0];
    const float* offset = (const float*)d_in[1];
    const float* weight = (const float*)d_in[2];
    float* out          = (float*)d_out;

    dim3 grid(H_, B_);  // 64 rows x 8 batches = 512 blocks
    deform_conv_relu_kernel<<<grid, 256, 0, stream>>>(x, offset, weight, out);
}

// Round 2
// 346.966 us; speedup vs baseline: 2.1254x; 2.1254x over previous
//
#include <hip/hip_runtime.h>

// Deformable Conv2D (B=8, C=256, H=W=64, K=3, s=1, p=1) + ReLU via bf16 MFMA.
//
// GEMM view: out[o, (b,h,w)] = sum_{k,c} W_k[o,c] * V_k[c,(b,h,w)]
//   kernel 1: weight [o][c][k] f32 -> Wbf [k][o][c] bf16 in d_ws (1.18 MB, L2)
//   kernel 2: block = (b, ho). Per (tap k, 32-ch chunk): bilinear-sample a
//             32c x 64pix B-tile into LDS (bf16, double-buffered), A-frags
//             loaded straight from global (coalesced 16B/lane), 16 MFMAs/wave.

#define B_  8
#define C_  256
#define H_  64
#define W_  64
#define K2_ 9
#define HW_ 4096

typedef short bf16x8 __attribute__((ext_vector_type(8)));
typedef float f32x4  __attribute__((ext_vector_type(4)));

__device__ __forceinline__ unsigned bfrne(float f) {
    unsigned u = __float_as_uint(f);
    u += 0x7fffu + ((u >> 16) & 1u);   // round-to-nearest-even bf16
    return u >> 16;
}

__global__ __launch_bounds__(256) void wtrans_kernel(
    const float* __restrict__ w, unsigned short* __restrict__ wbf) {
    const int t = blockIdx.x * 256 + threadIdx.x;   // over 9*256*256
    if (t >= K2_ * C_ * C_) return;
    const int k = t >> 16;          // C_*C_ = 65536
    const int o = (t >> 8) & 255;
    const int c = t & 255;
    wbf[t] = (unsigned short)bfrne(w[(o * C_ + c) * K2_ + k]);
}

__global__ __launch_bounds__(256) void deform_mfma_kernel(
    const float* __restrict__ x,              // [B, C, 64, 64]
    const float* __restrict__ offset,         // [B, 18, 64, 64]
    const unsigned short* __restrict__ wbf,   // [9][256][256] bf16
    float* __restrict__ out)                  // [B, 256, 64, 64]
{
    const int ho  = blockIdx.x;
    const int b   = blockIdx.y;
    const int tid = threadIdx.x;
    const int lane = tid & 63, wv = tid >> 6;
    const int lr = lane & 15, lg = lane >> 4;   // frag row/col, k-octet

    __shared__ int geom[K2_][W_][8];                 // [0..3] idx, [4..7] f32 wgt bits
    __shared__ unsigned short btile[2][W_ * 32];     // [pix][c] bf16, double-buffered

    // ---- geometry: 9 taps x 64 pixels, shared across all channels ----
    for (int e = tid; e < K2_ * W_; e += 256) {
        const int k  = e >> 6;
        const int wo = e & 63;
        const float offy = offset[((b * 18 + 2 * k    ) * H_ + ho) * W_ + wo];
        const float offx = offset[((b * 18 + 2 * k + 1) * H_ + ho) * W_ + wo];
        const float py = (float)(k / 3 + ho - 1) + offy;
        const float px = (float)(k % 3 + wo - 1) + offx;
        const float y0f = floorf(py), x0f = floorf(px);
        const int   y0 = (int)y0f,   x0 = (int)x0f;
        const float fy = py - y0f,   fx = px - x0f;
        const float wy[2] = {1.f - fy, fy};
        const float wx[2] = {1.f - fx, fx};
#pragma unroll
        for (int dy = 0; dy < 2; ++dy)
#pragma unroll
        for (int dx = 0; dx < 2; ++dx) {
            const int yy = y0 + dy, xx = x0 + dx;
            const bool ok = (yy >= 0) & (yy < H_) & (xx >= 0) & (xx < W_);
            geom[k][wo][dy * 2 + dx]     = ok ? (yy * W_ + xx) : 0;
            geom[k][wo][4 + dy * 2 + dx] = __float_as_int(ok ? wy[dy] * wx[dx] : 0.f);
        }
    }
    __syncthreads();

    f32x4 acc[16];
#pragma unroll
    for (int i = 0; i < 16; ++i) acc[i] = (f32x4)0.f;

    const int spix = tid >> 2;   // staging pixel (0..63)
    const int scg  = tid & 3;    // staging channel-octet (0..3)
    const float* xb = x + (size_t)b * C_ * HW_;

    int p = 0;
    for (int k = 0; k < K2_; ++k) {
        const int4 gi = *(const int4*)&geom[k][spix][0];
        const int4 gw = *(const int4*)&geom[k][spix][4];
        const float w0 = __int_as_float(gw.x), w1 = __int_as_float(gw.y);
        const float w2 = __int_as_float(gw.z), w3 = __int_as_float(gw.w);
        const unsigned short* wkbase =
            wbf + ((size_t)k * C_ + wv * 64 + lr) * C_ + lg * 8;

        for (int cc = 0; cc < 8; ++cc) {
            // A-fragments straight from global (L2-resident bf16 weights)
            bf16x8 af[4];
            const unsigned short* wp = wkbase + cc * 32;
#pragma unroll
            for (int mt = 0; mt < 4; ++mt)
                af[mt] = *(const bf16x8*)(wp + mt * 16 * C_);

            // bilinear-sample 8 channels for pixel spix -> bf16 pack
            const float* cb = xb + (size_t)(cc * 32 + scg * 8) * HW_;
            unsigned pk_[4];
#pragma unroll
            for (int i2 = 0; i2 < 4; ++i2) {
                const float* c0 = cb + (size_t)(2 * i2) * HW_;
                const float* c1 = cb + (size_t)(2 * i2 + 1) * HW_;
                const float va = w0 * c0[gi.x] + w1 * c0[gi.y]
                               + w2 * c0[gi.z] + w3 * c0[gi.w];
                const float vb = w0 * c1[gi.x] + w1 * c1[gi.y]
                               + w2 * c1[gi.z] + w3 * c1[gi.w];
                pk_[i2] = bfrne(va) | (bfrne(vb) << 16);
            }
            *(uint4*)&btile[p][tid * 8] = make_uint4(pk_[0], pk_[1], pk_[2], pk_[3]);

            __syncthreads();   // single barrier per step (double-buffered tile)

            // B-fragments + 16 MFMAs per wave
#pragma unroll
            for (int nt = 0; nt < 4; ++nt) {
                const bf16x8 bf_ =
                    *(const bf16x8*)&btile[p][(nt * 16 + lr) * 32 + lg * 8];
#pragma unroll
                for (int mt = 0; mt < 4; ++mt)
                    acc[mt * 4 + nt] = __builtin_amdgcn_mfma_f32_16x16x32_bf16(
                        af[mt], bf_, acc[mt * 4 + nt], 0, 0, 0);
            }
            p ^= 1;
        }
    }

    // ---- epilogue: ReLU + store (C/D layout: col=lane&15, row=(lane>>4)*4+r) ----
    const size_t ob = (size_t)b * C_ * HW_ + (size_t)ho * W_;
#pragma unroll
    for (int mt = 0; mt < 4; ++mt) {
        const int o0 = wv * 64 + mt * 16 + lg * 4;
#pragma unroll
        for (int nt = 0; nt < 4; ++nt) {
            const int wo = nt * 16 + lr;
#pragma unroll
            for (int r = 0; r < 4; ++r)
                out[ob + (size_t)(o0 + r) * HW_ + wo] =
                    fmaxf(acc[mt * 4 + nt][r], 0.f);
        }
    }
}

extern "C" void kernel_launch(void* const* d_in, const int* in_sizes, int n_in,
                              void* d_out, int out_size, void* d_ws, size_t ws_size,
                              hipStream_t stream) {
    const float* x      = (const float*)d_in[0];
    const float* offset = (const float*)d_in[1];
    const float* weight = (const float*)d_in[2];
    float* out          = (float*)d_out;
    unsigned short* wbf = (unsigned short*)d_ws;   // 9*256*256*2 = 1.18 MB

    wtrans_kernel<<<(K2_ * C_ * C_ + 255) / 256, 256, 0, stream>>>(weight, wbf);

    dim3 grid(H_, B_);   // 64 rows x 8 batches
    deform_mfma_kernel<<<grid, 256, 0, stream>>>(x, offset, wbf, out);
}

// Round 3
// 259.791 us; speedup vs baseline: 2.8386x; 1.3356x over previous
//
#include <hip/hip_runtime.h>

// Deformable Conv2D (B=8, C=256, H=W=64, K=3, s=1, p=1) + ReLU via bf16 MFMA.
//
// Round 2: gather-coalescing rework.
//  - lane = pixel: each corner-load instruction reads ONE channel at 64
//    near-consecutive columns (vs 64 scattered channel planes before)
//  - cc-outer / k-inner: 9 taps reuse the same 32-channel window in L1
//  - 1D grid, b = bid & 7  -> batch pinned to XCD (x[b]=4.2MB ~ L2/XCD)
//  - 512 threads (8 waves), 32 out-channels per wave -> 16 waves/CU
//  - B-tile rows padded to 80 B (20-bank stride) to kill 64B-stride conflicts

#define B_    8
#define C_    256
#define H_    64
#define W_    64
#define K2_   9
#define HW_   4096
#define ROWS_ 40   // B-tile row pitch in shorts (80 B)

typedef short bf16x8 __attribute__((ext_vector_type(8)));
typedef float f32x4  __attribute__((ext_vector_type(4)));

__device__ __forceinline__ unsigned bfrne(float f) {
    unsigned u = __float_as_uint(f);
    u += 0x7fffu + ((u >> 16) & 1u);   // round-to-nearest-even bf16
    return u >> 16;
}

__global__ __launch_bounds__(256) void wtrans_kernel(
    const float* __restrict__ w, unsigned short* __restrict__ wbf) {
    const int t = blockIdx.x * 256 + threadIdx.x;   // over 9*256*256
    if (t >= K2_ * C_ * C_) return;
    const int k = t >> 16;          // C_*C_ = 65536
    const int o = (t >> 8) & 255;
    const int c = t & 255;
    wbf[t] = (unsigned short)bfrne(w[(o * C_ + c) * K2_ + k]);
}

__global__ __launch_bounds__(512, 2) void deform_mfma_kernel(
    const float* __restrict__ x,              // [B, C, 64, 64]
    const float* __restrict__ offset,         // [B, 18, 64, 64]
    const unsigned short* __restrict__ wbf,   // [9][256][256] bf16
    float* __restrict__ out)                  // [B, 256, 64, 64]
{
    const int bid = blockIdx.x;
    const int b   = bid & 7;     // batch -> XCD (round-robin dispatch)
    const int ho  = bid >> 3;    // output row
    const int tid = threadIdx.x;
    const int lane = tid & 63;   // staging pixel; MFMA lane
    const int wv   = tid >> 6;   // wave 0..7
    const int lr = lane & 15, lg = lane >> 4;

    __shared__ int   gidx[K2_][4][W_];              // SoA gather indices
    __shared__ float gwt [K2_][4][W_];              // SoA bilinear weights
    __shared__ unsigned short btile[2][W_ * ROWS_]; // [pix][c], 80B pitch, dbuf

    // ---- geometry: 9 taps x 64 pixels (coalesced offset reads) ----
    for (int e = tid; e < K2_ * W_; e += 512) {
        const int k  = e >> 6;
        const int wo = e & 63;
        const float offy = offset[((b * 18 + 2 * k    ) * H_ + ho) * W_ + wo];
        const float offx = offset[((b * 18 + 2 * k + 1) * H_ + ho) * W_ + wo];
        const float py = (float)(k / 3 + ho - 1) + offy;
        const float px = (float)(k % 3 + wo - 1) + offx;
        const float y0f = floorf(py), x0f = floorf(px);
        const int   y0 = (int)y0f,   x0 = (int)x0f;
        const float fy = py - y0f,   fx = px - x0f;
        const float wy[2] = {1.f - fy, fy};
        const float wx[2] = {1.f - fx, fx};
#pragma unroll
        for (int dy = 0; dy < 2; ++dy)
#pragma unroll
        for (int dx = 0; dx < 2; ++dx) {
            const int yy = y0 + dy, xx = x0 + dx;
            const bool ok = (yy >= 0) & (yy < H_) & (xx >= 0) & (xx < W_);
            gidx[k][dy * 2 + dx][wo] = ok ? (yy * W_ + xx) : 0;
            gwt [k][dy * 2 + dx][wo] = ok ? wy[dy] * wx[dx] : 0.f;
        }
    }
    __syncthreads();

    f32x4 acc[2][4];
#pragma unroll
    for (int m = 0; m < 2; ++m)
#pragma unroll
        for (int n = 0; n < 4; ++n) acc[m][n] = (f32x4)0.f;

    const float* xb = x + (size_t)b * C_ * HW_;

    int p = 0;
    for (int cc = 0; cc < 8; ++cc) {
        // this wave stages 4 channels (cc*32 + wv*4 ..+3) for its pixel=lane
        const float* cb = xb + (size_t)(cc * 32 + wv * 4) * HW_;
        for (int k = 0; k < K2_; ++k) {
            const int   i0 = gidx[k][0][lane], i1 = gidx[k][1][lane];
            const int   i2 = gidx[k][2][lane], i3 = gidx[k][3][lane];
            const float w0 = gwt[k][0][lane], w1 = gwt[k][1][lane];
            const float w2 = gwt[k][2][lane], w3 = gwt[k][3][lane];
            unsigned pk[2];
#pragma unroll
            for (int q = 0; q < 2; ++q) {
                const float* c0 = cb + (size_t)(2 * q    ) * HW_;
                const float* c1 = cb + (size_t)(2 * q + 1) * HW_;
                const float va = w0 * c0[i0] + w1 * c0[i1]
                               + w2 * c0[i2] + w3 * c0[i3];
                const float vb = w0 * c1[i0] + w1 * c1[i1]
                               + w2 * c1[i2] + w3 * c1[i3];
                pk[q] = bfrne(va) | (bfrne(vb) << 16);
            }
            *(uint2*)&btile[p][lane * ROWS_ + wv * 4] = make_uint2(pk[0], pk[1]);

            // A-fragments straight from global (L2-resident bf16 weights)
            const unsigned short* wk =
                wbf + ((size_t)k * C_ + wv * 32 + lr) * C_ + cc * 32 + lg * 8;
            const bf16x8 af0 = *(const bf16x8*)wk;
            const bf16x8 af1 = *(const bf16x8*)(wk + 16 * C_);

            __syncthreads();   // B-tile ready (double-buffered: 1 barrier/step)

#pragma unroll
            for (int nt = 0; nt < 4; ++nt) {
                const bf16x8 bfv =
                    *(const bf16x8*)&btile[p][(nt * 16 + lr) * ROWS_ + lg * 8];
                acc[0][nt] = __builtin_amdgcn_mfma_f32_16x16x32_bf16(
                    af0, bfv, acc[0][nt], 0, 0, 0);
                acc[1][nt] = __builtin_amdgcn_mfma_f32_16x16x32_bf16(
                    af1, bfv, acc[1][nt], 0, 0, 0);
            }
            p ^= 1;
        }
    }

    // ---- epilogue: ReLU + store (C/D: col=lane&15, row=(lane>>4)*4+r) ----
    const size_t ob = (size_t)b * C_ * HW_ + (size_t)ho * W_;
#pragma unroll
    for (int mt = 0; mt < 2; ++mt) {
        const int o0 = wv * 32 + mt * 16 + lg * 4;
#pragma unroll
        for (int nt = 0; nt < 4; ++nt) {
            const int wo = nt * 16 + lr;
#pragma unroll
            for (int r = 0; r < 4; ++r)
                out[ob + (size_t)(o0 + r) * HW_ + wo] =
                    fmaxf(acc[mt][nt][r], 0.f);
        }
    }
}

extern "C" void kernel_launch(void* const* d_in, const int* in_sizes, int n_in,
                              void* d_out, int out_size, void* d_ws, size_t ws_size,
                              hipStream_t stream) {
    const float* x      = (const float*)d_in[0];
    const float* offset = (const float*)d_in[1];
    const float* weight = (const float*)d_in[2];
    float* out          = (float*)d_out;
    unsigned short* wbf = (unsigned short*)d_ws;   // 9*256*256*2 = 1.18 MB

    wtrans_kernel<<<(K2_ * C_ * C_ + 255) / 256, 256, 0, stream>>>(weight, wbf);

    deform_mfma_kernel<<<512, 512, 0, stream>>>(x, offset, wbf, out);
}

// Round 4
// 161.312 us; speedup vs baseline: 4.5715x; 1.6105x over previous
//
#include <hip/hip_runtime.h>

// Deformable Conv2D (B=8, C=256, H=W=64, K=3, s=1, p=1) + ReLU via bf16 MFMA.
//
// Round 3: gather-transaction reduction.
//  - x pre-packed as bf16 horizontal pairs: 1 aligned dword = 2 corners
//    (4 corner loads -> 2 pair loads, L1 transactions halved)
//  - weights pre-packed in MFMA A-fragment lane order (contiguous 1KB bursts)
//  - 256-thread blocks (19.7KB LDS) -> 4+ blocks/CU for latency hiding
//  - btile XOR-swizzled on 16B chunks: conflict-free b128 write & read
//  - b = bid&7 keeps batch pinned to one XCD's L2

#define B_   8
#define C_   256
#define H_   64
#define W_   64
#define K2_  9
#define HW_  4096

typedef short  bf16x8 __attribute__((ext_vector_type(8)));
typedef float  f32x4  __attribute__((ext_vector_type(4)));

__device__ __forceinline__ unsigned bfrne(float f) {
    unsigned u = __float_as_uint(f);
    u += 0x7fffu + ((u >> 16) & 1u);   // round-to-nearest-even bf16
    return u >> 16;
}

// ---- pack weights into MFMA A-fragment lane order ----
// dst[k][cc][t16][lg][lr][e]: oc = t16*16+lr, c = cc*32+lg*8+e
// wave load: lane (lr,lg) reads 16B at base + lane*16 -> contiguous 1KB
__global__ __launch_bounds__(256) void wpack_kernel(
    const float* __restrict__ w, unsigned short* __restrict__ wA) {
    const int t = blockIdx.x * 256 + threadIdx.x;   // source-linear (coalesced)
    if (t >= C_ * C_ * K2_) return;
    const int k = t % 9;
    const int c = (t / 9) & 255;
    const int o = t / (9 * 256);
    const int cc = c >> 5, lg = (c >> 3) & 3, e = c & 7;
    const int t16 = o >> 4, lr = o & 15;
    const int dst = e + 8 * (lr + 16 * (lg + 4 * (t16 + 16 * (cc + 8 * k))));
    wA[dst] = (unsigned short)bfrne(w[t]);
}

// ---- pack x into bf16 horizontal-pair planes: xd[i] = (bf(x[i]), bf(x[i+1])) ----
__global__ __launch_bounds__(256) void xpack_kernel(
    const float* __restrict__ x, unsigned* __restrict__ xd, int ntot) {
    const int i = blockIdx.x * 256 + threadIdx.x;
    const int p0 = i * 4;
    if (p0 >= ntot) return;
    const float4 v = *(const float4*)(x + p0);
    const float nxt = x[min(p0 + 4, ntot - 1)];
    uint4 r;
    r.x = bfrne(v.x) | (bfrne(v.y) << 16);
    r.y = bfrne(v.y) | (bfrne(v.z) << 16);
    r.z = bfrne(v.z) | (bfrne(v.w) << 16);
    r.w = bfrne(v.w) | (bfrne(nxt) << 16);
    *(uint4*)(xd + p0) = r;
}

// MODE 0: bf16 pair loads from xd; MODE 1: 4-corner f32 loads from x (fallback)
template<int MODE>
__global__ __launch_bounds__(256, 4) void deform_main(
    const float* __restrict__ x, const unsigned* __restrict__ xd,
    const float* __restrict__ offset, const unsigned short* __restrict__ wA,
    float* __restrict__ out)
{
    const int bid = blockIdx.x;
    const int b = bid & 7, ho = bid >> 3;   // batch -> XCD
    const int tid = threadIdx.x;
    const int lane = tid & 63, wv = tid >> 6;
    const int lr = lane & 15, lg = lane >> 4;

    __shared__ unsigned gaddr[K2_][W_];               // addr0|addr1<<13|s0<<26|s1<<27
    __shared__ float    gw[4][K2_][W_];               // w00,w01,w10,w11
    __shared__ alignas(16) unsigned short btile[2][W_ * 32];  // swizzled [pix][32ch]

    // ---- geometry: 9 taps x 64 pixels ----
    for (int e = tid; e < K2_ * W_; e += 256) {
        const int k = e >> 6, wo = e & 63;
        const float offy = offset[((b * 18 + 2 * k    ) * H_ + ho) * W_ + wo];
        const float offx = offset[((b * 18 + 2 * k + 1) * H_ + ho) * W_ + wo];
        const float py = (float)(k / 3 + ho - 1) + offy;
        const float px = (float)(k % 3 + wo - 1) + offx;
        const float y0f = floorf(py), x0f = floorf(px);
        const int   y0 = (int)y0f,   x0 = (int)x0f;
        const float fy = py - y0f,   fx = px - x0f;
        const float wy0 = (y0     >= 0 && y0     < H_) ? 1.f - fy : 0.f;
        const float wy1 = (y0 + 1 >= 0 && y0 + 1 < H_) ? fy       : 0.f;
        const float wx0 = (x0     >= 0 && x0     < W_) ? 1.f - fx : 0.f;
        const float wx1 = (x0 + 1 >= 0 && x0 + 1 < W_) ? fx       : 0.f;
        const int r0 = min(max(y0, 0), H_ - 1);
        const int r1 = min(max(y0 + 1, 0), H_ - 1);
        const int xs = min(max(x0, 0), W_ - 2);
        const int s0 = min(max(x0 - xs, 0), 1);
        const int s1 = min(max(x0 + 1 - xs, 0), 1);
        gaddr[k][wo] = (unsigned)(r0 * W_ + xs) | ((unsigned)(r1 * W_ + xs) << 13)
                     | ((unsigned)s0 << 26) | ((unsigned)s1 << 27);
        gw[0][k][wo] = wy0 * wx0;  gw[1][k][wo] = wy0 * wx1;
        gw[2][k][wo] = wy1 * wx0;  gw[3][k][wo] = wy1 * wx1;
    }
    __syncthreads();

    f32x4 acc[4][4];
#pragma unroll
    for (int m = 0; m < 4; ++m)
#pragma unroll
        for (int n = 0; n < 4; ++n) acc[m][n] = (f32x4)0.f;

    int p = 0;
    for (int cc = 0; cc < 8; ++cc) {
        // this wave stages channels cc*32 + wv*8 .. +8 for pixel = lane
        const unsigned* xdb = xd + ((size_t)(b * C_ + cc * 32 + wv * 8)) * HW_;
        const float*    xfb = x  + ((size_t)(b * C_ + cc * 32 + wv * 8)) * HW_;
        for (int k = 0; k < K2_; ++k) {
            const unsigned g = gaddr[k][lane];
            const int a0 = g & 8191, a1 = (g >> 13) & 8191;
            const int s0 = (g >> 26) & 1, s1 = (g >> 27) & 1;
            const float w00 = gw[0][k][lane], w01 = gw[1][k][lane];
            const float w10 = gw[2][k][lane], w11 = gw[3][k][lane];

            unsigned pk[4];
#pragma unroll
            for (int jp = 0; jp < 4; ++jp) {
                float vv[2];
#pragma unroll
                for (int h = 0; h < 2; ++h) {
                    const int j = jp * 2 + h;
                    float v00, v01, v10, v11;
                    if constexpr (MODE == 0) {
                        const unsigned* pl = xdb + (size_t)j * HW_;
                        const unsigned u0 = pl[a0], u1 = pl[a1];
                        const float lo0 = __uint_as_float(u0 << 16);
                        const float hi0 = __uint_as_float(u0 & 0xffff0000u);
                        const float lo1 = __uint_as_float(u1 << 16);
                        const float hi1 = __uint_as_float(u1 & 0xffff0000u);
                        v00 = s0 ? hi0 : lo0;  v01 = s1 ? hi0 : lo0;
                        v10 = s0 ? hi1 : lo1;  v11 = s1 ? hi1 : lo1;
                    } else {
                        const float* pl = xfb + (size_t)j * HW_;
                        v00 = pl[a0 + s0];  v01 = pl[a0 + s1];
                        v10 = pl[a1 + s0];  v11 = pl[a1 + s1];
                    }
                    vv[h] = w00 * v00 + w01 * v01 + w10 * v10 + w11 * v11;
                }
                pk[jp] = bfrne(vv[0]) | (bfrne(vv[1]) << 16);
            }
            // swizzled 16B store: chunk = wv ^ (pix&3)
            *(uint4*)&btile[p][lane * 32 + ((wv ^ (lane & 3)) * 8)] =
                make_uint4(pk[0], pk[1], pk[2], pk[3]);

            // A-fragments: contiguous 1KB per (k,cc,t16) tile
            const unsigned short* ap =
                wA + (((size_t)(k * 8 + cc) * 16 + wv * 4) * 64 + lane) * 8;
            bf16x8 af[4];
#pragma unroll
            for (int mt = 0; mt < 4; ++mt)
                af[mt] = *(const bf16x8*)(ap + (size_t)mt * 512);

            __syncthreads();   // btile[p] ready (dbuf: 1 barrier/step)

#pragma unroll
            for (int nt = 0; nt < 4; ++nt) {
                const int prow = nt * 16 + lr;
                const bf16x8 bfv = *(const bf16x8*)
                    &btile[p][prow * 32 + ((lg ^ (lr & 3)) * 8)];
#pragma unroll
                for (int mt = 0; mt < 4; ++mt)
                    acc[mt][nt] = __builtin_amdgcn_mfma_f32_16x16x32_bf16(
                        af[mt], bfv, acc[mt][nt], 0, 0, 0);
            }
            p ^= 1;
        }
    }

    // ---- epilogue: ReLU + store (C/D: col=lane&15 -> pixel, row=lg*4+r -> oc) ----
    const size_t ob = (size_t)b * C_ * HW_ + (size_t)ho * W_;
#pragma unroll
    for (int mt = 0; mt < 4; ++mt) {
        const int o0 = wv * 64 + mt * 16 + lg * 4;
#pragma unroll
        for (int nt = 0; nt < 4; ++nt) {
            const int wo = nt * 16 + lr;
#pragma unroll
            for (int r = 0; r < 4; ++r)
                out[ob + (size_t)(o0 + r) * HW_ + wo] =
                    fmaxf(acc[mt][nt][r], 0.f);
        }
    }
}

extern "C" void kernel_launch(void* const* d_in, const int* in_sizes, int n_in,
                              void* d_out, int out_size, void* d_ws, size_t ws_size,
                              hipStream_t stream) {
    const float* x      = (const float*)d_in[0];
    const float* offset = (const float*)d_in[1];
    const float* weight = (const float*)d_in[2];
    float* out          = (float*)d_out;

    const size_t wA_bytes = (size_t)K2_ * C_ * C_ * 2;          // 1.18 MB
    const size_t xd_off   = (wA_bytes + 255) & ~(size_t)255;
    const int    ntot     = B_ * C_ * HW_;                      // 8.39M pixels
    const size_t need     = xd_off + (size_t)ntot * 4;          // ~35.9 MB

    unsigned short* wAp = (unsigned short*)d_ws;
    unsigned*       xdp = (unsigned*)((char*)d_ws + xd_off);

    wpack_kernel<<<(C_ * C_ * K2_ + 255) / 256, 256, 0, stream>>>(weight, wAp);

    if (ws_size >= need) {
        xpack_kernel<<<(ntot / 4 + 255) / 256, 256, 0, stream>>>(x, xdp, ntot);
        deform_main<0><<<512, 256, 0, stream>>>(x, xdp, offset, wAp, out);
    } else {
        deform_main<1><<<512, 256, 0, stream>>>(x, xdp, offset, wAp, out);
    }
}

// Round 5
// 131.678 us; speedup vs baseline: 5.6003x; 1.2250x over previous
//
#include <hip/hip_runtime.h>

// Deformable Conv2D (B=8, C=256, H=W=64, K=3, s=1, p=1) + ReLU via bf16 MFMA.
//
// Round 4: quad-packed gathers + pipelined loads across raw barriers.
//  - xq[pix] = 2x2 corner quad as 4xbf16 (8B): ONE dwordx2 gather per
//    (tap,channel) sample; edge clamping folded into 4 quad-weights.
//  - 512-thr blocks (8 waves), lane=pixel: densest possible gather instrs
//  - step t+1 loads issued before barrier; s_waitcnt lgkmcnt(0)+s_barrier
//    keeps them in flight across the barrier (no vmcnt drain)
//  - even-XOR LDS swizzle: conflict-free b64 store / b128 read
//  - b = bid&7 pins batch to one XCD's L2

#define B_   8
#define C_   256
#define H_   64
#define W_   64
#define K2_  9
#define HW_  4096

typedef short  bf16x8 __attribute__((ext_vector_type(8)));
typedef float  f32x4  __attribute__((ext_vector_type(4)));

__device__ __forceinline__ unsigned bfrne(float f) {
    unsigned u = __float_as_uint(f);
    u += 0x7fffu + ((u >> 16) & 1u);
    return u >> 16;
}

// ---- weights into MFMA A-fragment lane order (same as round 3) ----
__global__ __launch_bounds__(256) void wpack_kernel(
    const float* __restrict__ w, unsigned short* __restrict__ wA) {
    const int t = blockIdx.x * 256 + threadIdx.x;
    if (t >= C_ * C_ * K2_) return;
    const int k = t % 9;
    const int c = (t / 9) & 255;
    const int o = t / (9 * 256);
    const int cc = c >> 5, lg = (c >> 3) & 3, e = c & 7;
    const int t16 = o >> 4, lr = o & 15;
    const int dst = e + 8 * (lr + 16 * (lg + 4 * (t16 + 16 * (cc + 8 * k))));
    wA[dst] = (unsigned short)bfrne(w[t]);
}

// ---- x -> 2x2 quad planes: xq[p]={bf(x[y][x]),bf(x[y][x+1]) | bf(x[y+1][x]),bf(x[y+1][x+1])}
__global__ __launch_bounds__(256) void xqpack_kernel(
    const float* __restrict__ x, uint2* __restrict__ xq) {
    const int t  = blockIdx.x * 256 + threadIdx.x;   // 2,097,152 threads
    const int p0 = t * 4;
    const int po = p0 & 4095;
    const int y  = po >> 6;
    const int x0 = po & 63;
    const int rows = p0 - x0;
    const float4 A = *(const float4*)(x + p0);
    const float nA = x[rows + (x0 == 60 ? 63 : x0 + 4)];
    const int rb = (y == 63) ? 0 : 64;
    const float4 Bv = *(const float4*)(x + p0 + rb);
    const float nB = x[rows + rb + (x0 == 60 ? 63 : x0 + 4)];
    const float Ae[5] = {A.x, A.y, A.z, A.w, nA};
    const float Be[5] = {Bv.x, Bv.y, Bv.z, Bv.w, nB};
    uint2 qv[4];
#pragma unroll
    for (int i = 0; i < 4; ++i) {
        qv[i].x = bfrne(Ae[i]) | (bfrne(Ae[i + 1]) << 16);
        qv[i].y = bfrne(Be[i]) | (bfrne(Be[i + 1]) << 16);
    }
    *(uint4*)&xq[p0]     = make_uint4(qv[0].x, qv[0].y, qv[1].x, qv[1].y);
    *(uint4*)&xq[p0 + 2] = make_uint4(qv[2].x, qv[2].y, qv[3].x, qv[3].y);
}

// MODE 0: quad loads from xq (pipelined). MODE 1: 4x f32 corner loads (fallback).
template<int MODE>
__global__ __launch_bounds__(512, 4) void deform_main(
    const float* __restrict__ x, const uint2* __restrict__ xq,
    const float* __restrict__ offset, const unsigned short* __restrict__ wA,
    float* __restrict__ out)
{
    const int bid = blockIdx.x;
    const int b = bid & 7, ho = bid >> 3;    // batch -> XCD
    const int tid = threadIdx.x;
    const int lane = tid & 63;               // staging pixel; MFMA lane
    const int wv   = tid >> 6;               // wave 0..7
    const int lr = lane & 15, lg = (lane >> 4) & 3;

    __shared__ int    gaddr[K2_][W_];                 // ys*64+xs (quad base)
    __shared__ float4 gwq[K2_][W_];                   // 4 quad weights
    __shared__ alignas(16) unsigned short btile[2][W_ * 32];  // [pix][32ch] swz

    // ---- geometry: quad base + quad weights (edge cases folded in) ----
    for (int e = tid; e < K2_ * W_; e += 512) {
        const int k = e >> 6, wo = e & 63;
        const float offy = offset[((b * 18 + 2 * k    ) * H_ + ho) * W_ + wo];
        const float offx = offset[((b * 18 + 2 * k + 1) * H_ + ho) * W_ + wo];
        const float py = (float)(k / 3 + ho - 1) + offy;
        const float px = (float)(k % 3 + wo - 1) + offx;
        const float y0f = floorf(py), x0f = floorf(px);
        const int   y0 = (int)y0f,   x0 = (int)x0f;
        const float fy = py - y0f,   fx = px - x0f;
        const float wy0 = (y0 >= 0  && y0 < H_)      ? 1.f - fy : 0.f;
        const float wy1 = (y0 >= -1 && y0 < H_ - 1)  ? fy       : 0.f;
        const float wx0 = (x0 >= 0  && x0 < W_)      ? 1.f - fx : 0.f;
        const float wx1 = (x0 >= -1 && x0 < W_ - 1)  ? fx       : 0.f;
        const int ys = min(max(y0, 0), H_ - 2);
        const int xs = min(max(x0, 0), W_ - 2);
        const float qy0 = (ys == y0 ? wy0 : 0.f) + (ys == y0 + 1 ? wy1 : 0.f);
        const float qy1 = (ys + 1 == y0 ? wy0 : 0.f) + (ys + 1 == y0 + 1 ? wy1 : 0.f);
        const float qx0 = (xs == x0 ? wx0 : 0.f) + (xs == x0 + 1 ? wx1 : 0.f);
        const float qx1 = (xs + 1 == x0 ? wx0 : 0.f) + (xs + 1 == x0 + 1 ? wx1 : 0.f);
        gaddr[k][wo] = ys * W_ + xs;
        gwq[k][wo] = make_float4(qy0 * qx0, qy0 * qx1, qy1 * qx0, qy1 * qx1);
    }
    __syncthreads();

    f32x4 acc[2][4];
#pragma unroll
    for (int m = 0; m < 2; ++m)
#pragma unroll
        for (int n = 0; n < 4; ++n) acc[m][n] = (f32x4)0.f;

    // wave wv stages channels cc*32 + wv*4 .. +3 for pixel = lane
    const uint2*  xqp = xq + ((size_t)(b * C_) + wv * 4) * HW_;   // cc=0 planes
    const float*  xfp = x  + ((size_t)(b * C_) + wv * 4) * HW_;

    uint2 q[4];
    if constexpr (MODE == 0) {          // prologue: loads for step (cc=0,k=0)
        const int a0 = gaddr[0][lane];
#pragma unroll
        for (int j = 0; j < 4; ++j) q[j] = xqp[(size_t)j * HW_ + a0];
    }

    int kk = 0;
    int p = 0;
    for (int s = 0; s < 72; ++s) {
        // A-fragments for current step (contiguous 1KB bursts, L2-resident)
        const int ccp = (MODE == 0) ? 0 : 0;  // cc folded into xqp pointer; recompute:
        // current cc = s / 9 tracked implicitly; ap needs it explicitly:
        const int cur_cc = s / 9;             // compiler strength-reduces (unrolled? keep simple)
        const unsigned short* ap =
            wA + (((size_t)(kk * 8 + cur_cc) * 16 + wv * 2) * 64 + lane) * 8;
        const bf16x8 af0 = *(const bf16x8*)ap;
        const bf16x8 af1 = *(const bf16x8*)(ap + 512);

        // ---- compute 4 samples ----
        const float4 wq = gwq[kk][lane];
        float vs[4];
        if constexpr (MODE == 0) {
#pragma unroll
            for (int j = 0; j < 4; ++j) {
                const float l0 = __uint_as_float(q[j].x << 16);
                const float h0 = __uint_as_float(q[j].x & 0xffff0000u);
                const float l1 = __uint_as_float(q[j].y << 16);
                const float h1 = __uint_as_float(q[j].y & 0xffff0000u);
                vs[j] = wq.x * l0 + wq.y * h0 + wq.z * l1 + wq.w * h1;
            }
        } else {
            const int a = gaddr[kk][lane];
#pragma unroll
            for (int j = 0; j < 4; ++j) {
                const float* pl = xfp + (size_t)j * HW_;
                vs[j] = wq.x * pl[a] + wq.y * pl[a + 1]
                      + wq.z * pl[a + W_] + wq.w * pl[a + W_ + 1];
            }
        }
        const unsigned pk0 = bfrne(vs[0]) | (bfrne(vs[1]) << 16);
        const unsigned pk1 = bfrne(vs[2]) | (bfrne(vs[3]) << 16);
        const int slot = wv ^ (((lane >> 1) & 3) << 1);
        *(uint2*)&btile[p][lane * 32 + slot * 4] = make_uint2(pk0, pk1);

        // ---- issue next step's quad loads (stay in flight across barrier) ----
        if (s < 71) {
            int kn = kk + 1;
            if (kn == 9) {
                kn = 0;
                xqp += (size_t)32 * HW_;
                xfp += (size_t)32 * HW_;
            }
            kk = kn;
            if constexpr (MODE == 0) {
                const int an = gaddr[kn][lane];
#pragma unroll
                for (int j = 0; j < 4; ++j) q[j] = xqp[(size_t)j * HW_ + an];
            }
        }

        asm volatile("s_waitcnt lgkmcnt(0)" ::: "memory");
        __builtin_amdgcn_s_barrier();

        // ---- 8 MFMAs from btile[p] ----
#pragma unroll
        for (int nt = 0; nt < 4; ++nt) {
            const int prow = nt * 16 + lr;
            const int rs = (2 * lg) ^ (((prow >> 1) & 3) << 1);
            const bf16x8 bv = *(const bf16x8*)&btile[p][prow * 32 + rs * 4];
            acc[0][nt] = __builtin_amdgcn_mfma_f32_16x16x32_bf16(af0, bv, acc[0][nt], 0, 0, 0);
            acc[1][nt] = __builtin_amdgcn_mfma_f32_16x16x32_bf16(af1, bv, acc[1][nt], 0, 0, 0);
        }
        p ^= 1;
    }

    // ---- epilogue: ReLU + store ----
    const size_t ob = (size_t)b * C_ * HW_ + (size_t)ho * W_;
#pragma unroll
    for (int mt = 0; mt < 2; ++mt) {
        const int o0 = wv * 32 + mt * 16 + lg * 4;
#pragma unroll
        for (int nt = 0; nt < 4; ++nt) {
            const int wo = nt * 16 + lr;
#pragma unroll
            for (int r = 0; r < 4; ++r)
                out[ob + (size_t)(o0 + r) * HW_ + wo] =
                    fmaxf(acc[mt][nt][r], 0.f);
        }
    }
}

extern "C" void kernel_launch(void* const* d_in, const int* in_sizes, int n_in,
                              void* d_out, int out_size, void* d_ws, size_t ws_size,
                              hipStream_t stream) {
    const float* x      = (const float*)d_in[0];
    const float* offset = (const float*)d_in[1];
    const float* weight = (const float*)d_in[2];
    float* out          = (float*)d_out;

    const size_t wA_bytes = (size_t)K2_ * C_ * C_ * 2;   // 1.18 MB (256-aligned)
    const size_t xq_off   = wA_bytes;
    const size_t ntot     = (size_t)B_ * C_ * HW_;       // 8.39M pixels
    const size_t need     = xq_off + ntot * 8;           // ~68.3 MB

    unsigned short* wAp = (unsigned short*)d_ws;
    uint2*          xqp = (uint2*)((char*)d_ws + xq_off);

    wpack_kernel<<<(C_ * C_ * K2_ + 255) / 256, 256, 0, stream>>>(weight, wAp);

    if (ws_size >= need) {
        xqpack_kernel<<<(int)(ntot / 4 / 256), 256, 0, stream>>>(x, xqp);
        deform_main<0><<<512, 512, 0, stream>>>(x, xqp, offset, wAp, out);
    } else {
        deform_main<1><<<512, 512, 0, stream>>>(x, xqp, offset, wAp, out);
    }
}

// Round 7
// 123.872 us; speedup vs baseline: 5.9533x; 1.0630x over previous
//
#include <hip/hip_runtime.h>

// Deformable Conv2D (B=8, C=256, H=W=64, K=3, s=1, p=1) + ReLU via fp16 MFMA.
//
// Round 6 = round 5 with the half-type fix (__fp16 vectors to match clang's
// builtin signatures for cvt_pkrtz / fdot2 / mfma_f32_16x16x32_f16).
//  - xq2[c/2][pix] = 16B cell {top/bot fp16 corner pairs for ch c, c+1}
//    -> ONE dwordx4 gather = 2 channels' 4 corners (2 loads/wave/step)
//  - bilinear = 2 x v_dot2_f32_f16 per channel
//  - q loads issued 2 steps ahead (named qA/qB sets, manual unroll-2)
//  - lgkmcnt(0)-only barrier keeps global loads in flight across it
//  - mfma_f32_16x16x32_f16; A pre-packed in fragment lane order (fp16)

#define B_   8
#define C_   256
#define H_   64
#define W_   64
#define K2_  9
#define HW_  4096

typedef __fp16 f16x2 __attribute__((ext_vector_type(2)));
typedef __fp16 f16x8 __attribute__((ext_vector_type(8)));
typedef float  f32x4 __attribute__((ext_vector_type(4)));

static __device__ __forceinline__ f16x2 u2h(unsigned u) {
    union { unsigned u; f16x2 h; } v; v.u = u; return v.h;
}
static __device__ __forceinline__ unsigned h2u(f16x2 h) {
    union { unsigned u; f16x2 h; } v; v.h = h; return v.u;
}

// ---- weights -> fp16, MFMA A-fragment lane order ----
__global__ __launch_bounds__(256) void wpack_kernel(
    const float* __restrict__ w, unsigned short* __restrict__ wA) {
    const int t = blockIdx.x * 256 + threadIdx.x;
    if (t >= C_ * C_ * K2_) return;
    const int k = t % 9;
    const int c = (t / 9) & 255;
    const int o = t / (9 * 256);
    const int cc = c >> 5, lg = (c >> 3) & 3, e = c & 7;
    const int t16 = o >> 4, lr = o & 15;
    const int dst = e + 8 * (lr + 16 * (lg + 4 * (t16 + 16 * (cc + 8 * k))));
    const __fp16 h = (__fp16)w[t];
    unsigned short us;
    __builtin_memcpy(&us, &h, 2);
    wA[dst] = us;
}

// ---- x -> fp16 2x2 quads, channel-paired 16B cells ----
// cell[gc2*HW + pix] = {top(c=2gc2), bot(c=2gc2), top(c=2gc2+1), bot(c=2gc2+1)}
__global__ __launch_bounds__(256) void xq2pack_kernel(
    const float* __restrict__ x, uint4* __restrict__ xq2) {
    const int t = blockIdx.x * 256 + threadIdx.x;     // B*C/2*1024 threads
    const int pix4 = (t & 1023) * 4;
    const int gc2  = t >> 10;
    const int y  = pix4 >> 6;
    const int x0 = pix4 & 63;
    const int rb = (y == 63) ? 0 : W_;
    const int nx = (x0 == 60) ? 3 : 4;
    const float* p0 = x + (size_t)(2 * gc2) * HW_ + pix4;
    const float* p1 = p0 + HW_;
    const float4 A0 = *(const float4*)p0;        const float nA0 = p0[nx];
    const float4 B0 = *(const float4*)(p0 + rb); const float nB0 = p0[rb + nx];
    const float4 A1 = *(const float4*)p1;        const float nA1 = p1[nx];
    const float4 B1 = *(const float4*)(p1 + rb); const float nB1 = p1[rb + nx];
    const float a0[5] = {A0.x, A0.y, A0.z, A0.w, nA0};
    const float b0[5] = {B0.x, B0.y, B0.z, B0.w, nB0};
    const float a1[5] = {A1.x, A1.y, A1.z, A1.w, nA1};
    const float b1[5] = {B1.x, B1.y, B1.z, B1.w, nB1};
    uint4* dst = xq2 + (size_t)gc2 * HW_ + pix4;
#pragma unroll
    for (int i = 0; i < 4; ++i) {
        uint4 cell;
        cell.x = h2u(__builtin_amdgcn_cvt_pkrtz(a0[i], a0[i + 1]));
        cell.y = h2u(__builtin_amdgcn_cvt_pkrtz(b0[i], b0[i + 1]));
        cell.z = h2u(__builtin_amdgcn_cvt_pkrtz(a1[i], a1[i + 1]));
        cell.w = h2u(__builtin_amdgcn_cvt_pkrtz(b1[i], b1[i + 1]));
        dst[i] = cell;
    }
}

// MODE 0: paired fp16 quad gathers, depth-2 pipelined. MODE 1: f32 fallback.
template<int MODE>
__global__ __launch_bounds__(512, 4) void deform_main(
    const float* __restrict__ x, const uint4* __restrict__ xq2,
    const float* __restrict__ offset, const unsigned short* __restrict__ wA,
    float* __restrict__ out)
{
    const int bid = blockIdx.x;
    const int b = bid & 7, ho = bid >> 3;     // batch -> XCD
    const int tid = threadIdx.x;
    const int lane = tid & 63;                // staging pixel; MFMA lane
    const int wv   = tid >> 6;                // wave 0..7
    const int lr = lane & 15, lg = (lane >> 4) & 3;

    __shared__ int   gaddr[K2_][W_];          // quad base ys*64+xs
    __shared__ uint2 gw2[K2_][W_];            // fp16 pairs (w00,w01),(w10,w11)
    __shared__ alignas(16) unsigned short btile[2][W_ * 32];

    // ---- geometry ----
    for (int e = tid; e < K2_ * W_; e += 512) {
        const int k = e >> 6, wo = e & 63;
        const float offy = offset[((b * 18 + 2 * k    ) * H_ + ho) * W_ + wo];
        const float offx = offset[((b * 18 + 2 * k + 1) * H_ + ho) * W_ + wo];
        const float py = (float)(k / 3 + ho - 1) + offy;
        const float px = (float)(k % 3 + wo - 1) + offx;
        const float y0f = floorf(py), x0f = floorf(px);
        const int   y0 = (int)y0f,   x0 = (int)x0f;
        const float fy = py - y0f,   fx = px - x0f;
        const float wy0 = (y0 >= 0  && y0 < H_)     ? 1.f - fy : 0.f;
        const float wy1 = (y0 >= -1 && y0 < H_ - 1) ? fy       : 0.f;
        const float wx0 = (x0 >= 0  && x0 < W_)     ? 1.f - fx : 0.f;
        const float wx1 = (x0 >= -1 && x0 < W_ - 1) ? fx       : 0.f;
        const int ys = min(max(y0, 0), H_ - 2);
        const int xs = min(max(x0, 0), W_ - 2);
        const float qy0 = (ys == y0 ? wy0 : 0.f) + (ys == y0 + 1 ? wy1 : 0.f);
        const float qy1 = (ys + 1 == y0 ? wy0 : 0.f) + (ys + 1 == y0 + 1 ? wy1 : 0.f);
        const float qx0 = (xs == x0 ? wx0 : 0.f) + (xs == x0 + 1 ? wx1 : 0.f);
        const float qx1 = (xs + 1 == x0 ? wx0 : 0.f) + (xs + 1 == x0 + 1 ? wx1 : 0.f);
        gaddr[k][wo] = ys * W_ + xs;
        gw2[k][wo] = make_uint2(
            h2u(__builtin_amdgcn_cvt_pkrtz(qy0 * qx0, qy0 * qx1)),
            h2u(__builtin_amdgcn_cvt_pkrtz(qy1 * qx0, qy1 * qx1)));
    }
    __syncthreads();

    f32x4 acc[2][4];
#pragma unroll
    for (int m = 0; m < 2; ++m)
#pragma unroll
        for (int n = 0; n < 4; ++n) acc[m][n] = (f32x4)0.f;

    const __fp16* wAh = (const __fp16*)wA;

    if constexpr (MODE == 0) {
        // wave wv: channels cc*32 + wv*4 .. +3  ->  c2 = cc*16 + wv*2 + {0,1}
        const uint4* xqb = xq2 + ((size_t)(b * (C_ / 2)) + wv * 2) * HW_;

        // issue state (2 steps ahead)
        int kP = 0, ccP = 0;
        const uint4* pP = xqb;
        uint4 qA0, qA1, qB0, qB1;
        { const int a = gaddr[0][lane]; qA0 = pP[a]; qA1 = pP[HW_ + a]; }
        { const int a = gaddr[1][lane]; qB0 = pP[a]; qB1 = pP[HW_ + a]; }
        kP = 2;

        int kC = 0, ccC = 0;
        int p = 0;

#define STEP_BODY(Q0, Q1)                                                      \
        {                                                                      \
            const __fp16* ap = wAh +                                           \
                (((size_t)(kC * 8 + ccC) * 16 + wv * 2) * 64 + lane) * 8;      \
            const f16x8 af0 = *(const f16x8*)ap;                               \
            const f16x8 af1 = *(const f16x8*)(ap + 512);                       \
            const uint2 wp = *(const uint2*)&gw2[kC][lane];                    \
            const f16x2 wt = u2h(wp.x), wb = u2h(wp.y);                        \
            const float vs0 = __builtin_amdgcn_fdot2(u2h(Q0.y), wb,            \
                __builtin_amdgcn_fdot2(u2h(Q0.x), wt, 0.f, false), false);     \
            const float vs1 = __builtin_amdgcn_fdot2(u2h(Q0.w), wb,            \
                __builtin_amdgcn_fdot2(u2h(Q0.z), wt, 0.f, false), false);     \
            const float vs2 = __builtin_amdgcn_fdot2(u2h(Q1.y), wb,            \
                __builtin_amdgcn_fdot2(u2h(Q1.x), wt, 0.f, false), false);     \
            const float vs3 = __builtin_amdgcn_fdot2(u2h(Q1.w), wb,            \
                __builtin_amdgcn_fdot2(u2h(Q1.z), wt, 0.f, false), false);     \
            const unsigned pk0 = h2u(__builtin_amdgcn_cvt_pkrtz(vs0, vs1));    \
            const unsigned pk1 = h2u(__builtin_amdgcn_cvt_pkrtz(vs2, vs3));    \
            const int slot = wv ^ (((lane >> 1) & 3) << 1);                    \
            *(uint2*)&btile[p][lane * 32 + slot * 4] = make_uint2(pk0, pk1);   \
            { const int a2 = gaddr[kP][lane];                                  \
              Q0 = pP[a2]; Q1 = pP[HW_ + a2]; }                                \
            if (++kP == 9) { kP = 0; pP += (size_t)16 * HW_;                   \
                             if (++ccP == 8) { ccP = 0; pP = xqb; } }          \
            asm volatile("s_waitcnt lgkmcnt(0)" ::: "memory");                 \
            __builtin_amdgcn_s_barrier();                                      \
            _Pragma("unroll")                                                  \
            for (int nt = 0; nt < 4; ++nt) {                                   \
                const int prow = nt * 16 + lr;                                 \
                const int rs = (2 * lg) ^ (((prow >> 1) & 3) << 1);            \
                const f16x8 bv = *(const f16x8*)&btile[p][prow * 32 + rs * 4]; \
                acc[0][nt] = __builtin_amdgcn_mfma_f32_16x16x32_f16(           \
                    af0, bv, acc[0][nt], 0, 0, 0);                             \
                acc[1][nt] = __builtin_amdgcn_mfma_f32_16x16x32_f16(           \
                    af1, bv, acc[1][nt], 0, 0, 0);                             \
            }                                                                  \
            p ^= 1;                                                            \
            if (++kC == 9) { kC = 0; ++ccC; }                                  \
        }

        for (int it = 0; it < 36; ++it) {
            STEP_BODY(qA0, qA1)   // even step
            STEP_BODY(qB0, qB1)   // odd step
        }
#undef STEP_BODY
    } else {
        // fallback: direct f32 corner loads, one __syncthreads per step
        const float* xfp = x + ((size_t)(b * C_) + wv * 4) * HW_;
        int p = 0;
        int kC = 0, ccC = 0;
        for (int s = 0; s < 72; ++s) {
            const __fp16* ap = wAh +
                (((size_t)(kC * 8 + ccC) * 16 + wv * 2) * 64 + lane) * 8;
            const f16x8 af0 = *(const f16x8*)ap;
            const f16x8 af1 = *(const f16x8*)(ap + 512);
            const uint2 wp = *(const uint2*)&gw2[kC][lane];
            const f16x2 wt = u2h(wp.x), wb = u2h(wp.y);
            const float w00 = (float)wt.x, w01 = (float)wt.y;
            const float w10 = (float)wb.x, w11 = (float)wb.y;
            const int a = gaddr[kC][lane];
            float vs[4];
#pragma unroll
            for (int j = 0; j < 4; ++j) {
                const float* pl = xfp + (size_t)(ccC * 32 + j) * HW_;
                vs[j] = w00 * pl[a] + w01 * pl[a + 1]
                      + w10 * pl[a + W_] + w11 * pl[a + W_ + 1];
            }
            const unsigned pk0 = h2u(__builtin_amdgcn_cvt_pkrtz(vs[0], vs[1]));
            const unsigned pk1 = h2u(__builtin_amdgcn_cvt_pkrtz(vs[2], vs[3]));
            const int slot = wv ^ (((lane >> 1) & 3) << 1);
            *(uint2*)&btile[p][lane * 32 + slot * 4] = make_uint2(pk0, pk1);
            __syncthreads();
#pragma unroll
            for (int nt = 0; nt < 4; ++nt) {
                const int prow = nt * 16 + lr;
                const int rs = (2 * lg) ^ (((prow >> 1) & 3) << 1);
                const f16x8 bv = *(const f16x8*)&btile[p][prow * 32 + rs * 4];
                acc[0][nt] = __builtin_amdgcn_mfma_f32_16x16x32_f16(
                    af0, bv, acc[0][nt], 0, 0, 0);
                acc[1][nt] = __builtin_amdgcn_mfma_f32_16x16x32_f16(
                    af1, bv, acc[1][nt], 0, 0, 0);
            }
            p ^= 1;
            if (++kC == 9) { kC = 0; ++ccC; }
        }
    }

    // ---- epilogue: ReLU + store (C/D: col=lane&15 -> pixel, row=lg*4+r -> oc)
    const size_t ob = (size_t)b * C_ * HW_ + (size_t)ho * W_;
#pragma unroll
    for (int mt = 0; mt < 2; ++mt) {
        const int o0 = wv * 32 + mt * 16 + lg * 4;
#pragma unroll
        for (int nt = 0; nt < 4; ++nt) {
            const int wo = nt * 16 + lr;
#pragma unroll
            for (int r = 0; r < 4; ++r)
                out[ob + (size_t)(o0 + r) * HW_ + wo] =
                    fmaxf(acc[mt][nt][r], 0.f);
        }
    }
}

extern "C" void kernel_launch(void* const* d_in, const int* in_sizes, int n_in,
                              void* d_out, int out_size, void* d_ws, size_t ws_size,
                              hipStream_t stream) {
    const float* x      = (const float*)d_in[0];
    const float* offset = (const float*)d_in[1];
    const float* weight = (const float*)d_in[2];
    float* out          = (float*)d_out;

    const size_t wA_bytes = (size_t)K2_ * C_ * C_ * 2;        // 1.18 MB
    const size_t xq_off   = wA_bytes;                         // 16B-aligned
    const size_t ncell    = (size_t)B_ * (C_ / 2) * HW_;      // 4.19M cells
    const size_t need     = xq_off + ncell * 16;              // ~68.3 MB

    unsigned short* wAp = (unsigned short*)d_ws;
    uint4*          xqp = (uint4*)((char*)d_ws + xq_off);

    wpack_kernel<<<(C_ * C_ * K2_ + 255) / 256, 256, 0, stream>>>(weight, wAp);

    if (ws_size >= need) {
        xq2pack_kernel<<<(int)(ncell / 4 / 256), 256, 0, stream>>>(x, xqp);
        deform_main<0><<<512, 512, 0, stream>>>(x, xqp, offset, wAp, out);
    } else {
        deform_main<1><<<512, 512, 0, stream>>>(x, xqp, offset, wAp, out);
    }
}

// Round 8
// 120.311 us; speedup vs baseline: 6.1294x; 1.0296x over previous
//
#include <hip/hip_runtime.h>

// Deformable Conv2D (B=8, C=256, H=W=64, K=3, s=1, p=1) + ReLU via fp16 MFMA.
//
// Round 7: fat-phase restructure — barrier count 144 -> 16.
//  cc-loop (8): [stage: 9 taps sampled per lane, 18 gathers 4-pair pipelined,
//               fat 64x288 LDS tile] barrier [mfma: 72 MFMAs + A-loads] barrier
//  - btile pitch 296 f16 (592B): b128 reads 2-way (free), aligned 16B
//  - gathers/A-loads all consumed in-phase -> barriers drain nothing
//  - xq2 16B channel-paired corner cells + fp16 dot2 sampling (validated r6)

#define B_     8
#define C_     256
#define H_     64
#define W_     64
#define K2_    9
#define HW_    4096
#define PITCH_ 296   // btile row pitch in f16 units (592 B)

typedef __fp16 f16x2 __attribute__((ext_vector_type(2)));
typedef __fp16 f16x8 __attribute__((ext_vector_type(8)));
typedef float  f32x4 __attribute__((ext_vector_type(4)));

static __device__ __forceinline__ f16x2 u2h(unsigned u) {
    union { unsigned u; f16x2 h; } v; v.u = u; return v.h;
}
static __device__ __forceinline__ unsigned h2u(f16x2 h) {
    union { unsigned u; f16x2 h; } v; v.h = h; return v.u;
}

// ---- weights -> fp16, MFMA A-fragment lane order (unchanged, validated) ----
__global__ __launch_bounds__(256) void wpack_kernel(
    const float* __restrict__ w, unsigned short* __restrict__ wA) {
    const int t = blockIdx.x * 256 + threadIdx.x;
    if (t >= C_ * C_ * K2_) return;
    const int k = t % 9;
    const int c = (t / 9) & 255;
    const int o = t / (9 * 256);
    const int cc = c >> 5, lg = (c >> 3) & 3, e = c & 7;
    const int t16 = o >> 4, lr = o & 15;
    const int dst = e + 8 * (lr + 16 * (lg + 4 * (t16 + 16 * (cc + 8 * k))));
    const __fp16 h = (__fp16)w[t];
    unsigned short us;
    __builtin_memcpy(&us, &h, 2);
    wA[dst] = us;
}

// ---- x -> fp16 2x2 quads, channel-paired 16B cells (unchanged, validated) ----
__global__ __launch_bounds__(256) void xq2pack_kernel(
    const float* __restrict__ x, uint4* __restrict__ xq2) {
    const int t = blockIdx.x * 256 + threadIdx.x;     // B*C/2*1024 threads
    const int pix4 = (t & 1023) * 4;
    const int gc2  = t >> 10;
    const int y  = pix4 >> 6;
    const int x0 = pix4 & 63;
    const int rb = (y == 63) ? 0 : W_;
    const int nx = (x0 == 60) ? 3 : 4;
    const float* p0 = x + (size_t)(2 * gc2) * HW_ + pix4;
    const float* p1 = p0 + HW_;
    const float4 A0 = *(const float4*)p0;        const float nA0 = p0[nx];
    const float4 B0 = *(const float4*)(p0 + rb); const float nB0 = p0[rb + nx];
    const float4 A1 = *(const float4*)p1;        const float nA1 = p1[nx];
    const float4 B1 = *(const float4*)(p1 + rb); const float nB1 = p1[rb + nx];
    const float a0[5] = {A0.x, A0.y, A0.z, A0.w, nA0};
    const float b0[5] = {B0.x, B0.y, B0.z, B0.w, nB0};
    const float a1[5] = {A1.x, A1.y, A1.z, A1.w, nA1};
    const float b1[5] = {B1.x, B1.y, B1.z, B1.w, nB1};
    uint4* dst = xq2 + (size_t)gc2 * HW_ + pix4;
#pragma unroll
    for (int i = 0; i < 4; ++i) {
        uint4 cell;
        cell.x = h2u(__builtin_amdgcn_cvt_pkrtz(a0[i], a0[i + 1]));
        cell.y = h2u(__builtin_amdgcn_cvt_pkrtz(b0[i], b0[i + 1]));
        cell.z = h2u(__builtin_amdgcn_cvt_pkrtz(a1[i], a1[i + 1]));
        cell.w = h2u(__builtin_amdgcn_cvt_pkrtz(b1[i], b1[i + 1]));
        dst[i] = cell;
    }
}

// MODE 0: 16B cell gathers from xq2. MODE 1: f32 corner loads (fallback).
template<int MODE>
__global__ __launch_bounds__(512, 4) void deform_main(
    const float* __restrict__ x, const uint4* __restrict__ xq2,
    const float* __restrict__ offset, const unsigned short* __restrict__ wA,
    float* __restrict__ out)
{
    const int bid = blockIdx.x;
    const int b = bid & 7, ho = bid >> 3;     // batch -> XCD
    const int tid = threadIdx.x;
    const int lane = tid & 63;                // staging pixel; MFMA lane
    const int wv   = tid >> 6;                // wave 0..7
    const int lr = lane & 15, lg = (lane >> 4) & 3;

    __shared__ int   gaddr[K2_][W_];          // quad base ys*64+xs
    __shared__ uint2 gw2[K2_][W_];            // fp16 pairs (w00,w01),(w10,w11)
    __shared__ alignas(16) unsigned short btile[W_ * PITCH_];  // 37.9 KB

    // ---- geometry: 9 taps x 64 pixels (unchanged, validated) ----
    for (int e = tid; e < K2_ * W_; e += 512) {
        const int k = e >> 6, wo = e & 63;
        const float offy = offset[((b * 18 + 2 * k    ) * H_ + ho) * W_ + wo];
        const float offx = offset[((b * 18 + 2 * k + 1) * H_ + ho) * W_ + wo];
        const float py = (float)(k / 3 + ho - 1) + offy;
        const float px = (float)(k % 3 + wo - 1) + offx;
        const float y0f = floorf(py), x0f = floorf(px);
        const int   y0 = (int)y0f,   x0 = (int)x0f;
        const float fy = py - y0f,   fx = px - x0f;
        const float wy0 = (y0 >= 0  && y0 < H_)     ? 1.f - fy : 0.f;
        const float wy1 = (y0 >= -1 && y0 < H_ - 1) ? fy       : 0.f;
        const float wx0 = (x0 >= 0  && x0 < W_)     ? 1.f - fx : 0.f;
        const float wx1 = (x0 >= -1 && x0 < W_ - 1) ? fx       : 0.f;
        const int ys = min(max(y0, 0), H_ - 2);
        const int xs = min(max(x0, 0), W_ - 2);
        const float qy0 = (ys == y0 ? wy0 : 0.f) + (ys == y0 + 1 ? wy1 : 0.f);
        const float qy1 = (ys + 1 == y0 ? wy0 : 0.f) + (ys + 1 == y0 + 1 ? wy1 : 0.f);
        const float qx0 = (xs == x0 ? wx0 : 0.f) + (xs == x0 + 1 ? wx1 : 0.f);
        const float qx1 = (xs + 1 == x0 ? wx0 : 0.f) + (xs + 1 == x0 + 1 ? wx1 : 0.f);
        gaddr[k][wo] = ys * W_ + xs;
        gw2[k][wo] = make_uint2(
            h2u(__builtin_amdgcn_cvt_pkrtz(qy0 * qx0, qy0 * qx1)),
            h2u(__builtin_amdgcn_cvt_pkrtz(qy1 * qx0, qy1 * qx1)));
    }
    __syncthreads();

    f32x4 acc[2][4];
#pragma unroll
    for (int m = 0; m < 2; ++m)
#pragma unroll
        for (int n = 0; n < 4; ++n) acc[m][n] = (f32x4)0.f;

    const __fp16* wAh = (const __fp16*)wA;
    // wave wv: channels cc*32 + wv*4 .. +3  ->  cell planes cc*16 + wv*2 + {0,1}
    const uint4* xqb = xq2 + ((size_t)(b * (C_ / 2)) + wv * 2) * HW_;
    const float* xfb = x + ((size_t)(b * C_) + wv * 4) * HW_;

    for (int cc = 0; cc < 8; ++cc) {
        const uint4* pP = xqb + (size_t)cc * 16 * HW_;

        // ================= STAGE PHASE: 9 taps, 4-pair-deep pipeline ========
        uint4 qa[4], qb[4];
        if constexpr (MODE == 0) {
#pragma unroll
            for (int k = 0; k < 4; ++k) {
                const int a = gaddr[k][lane];
                qa[k] = pP[a];
                qb[k] = pP[HW_ + a];
            }
        }
#pragma unroll
        for (int k = 0; k < K2_; ++k) {
            uint4 q0, q1;
            if constexpr (MODE == 0) {
                q0 = qa[k & 3];
                q1 = qb[k & 3];
                if (k + 4 < K2_) {                 // compile-time per copy
                    const int a = gaddr[k + 4][lane];
                    qa[k & 3] = pP[a];             // (k+4)&3 == k&3
                    qb[k & 3] = pP[HW_ + a];
                }
            } else {
                const int a = gaddr[k][lane];
                const float* p0 = xfb + (size_t)(cc * 32) * HW_;
                const float* p1 = p0 + HW_;
                const float* p2 = p1 + HW_;
                const float* p3 = p2 + HW_;
                q0.x = h2u(__builtin_amdgcn_cvt_pkrtz(p0[a], p0[a + 1]));
                q0.y = h2u(__builtin_amdgcn_cvt_pkrtz(p0[a + W_], p0[a + W_ + 1]));
                q0.z = h2u(__builtin_amdgcn_cvt_pkrtz(p1[a], p1[a + 1]));
                q0.w = h2u(__builtin_amdgcn_cvt_pkrtz(p1[a + W_], p1[a + W_ + 1]));
                q1.x = h2u(__builtin_amdgcn_cvt_pkrtz(p2[a], p2[a + 1]));
                q1.y = h2u(__builtin_amdgcn_cvt_pkrtz(p2[a + W_], p2[a + W_ + 1]));
                q1.z = h2u(__builtin_amdgcn_cvt_pkrtz(p3[a], p3[a + 1]));
                q1.w = h2u(__builtin_amdgcn_cvt_pkrtz(p3[a + W_], p3[a + W_ + 1]));
            }
            const uint2 wp = gw2[k][lane];
            const f16x2 wt = u2h(wp.x), wb = u2h(wp.y);
            const float vs0 = __builtin_amdgcn_fdot2(u2h(q0.y), wb,
                __builtin_amdgcn_fdot2(u2h(q0.x), wt, 0.f, false), false);
            const float vs1 = __builtin_amdgcn_fdot2(u2h(q0.w), wb,
                __builtin_amdgcn_fdot2(u2h(q0.z), wt, 0.f, false), false);
            const float vs2 = __builtin_amdgcn_fdot2(u2h(q1.y), wb,
                __builtin_amdgcn_fdot2(u2h(q1.x), wt, 0.f, false), false);
            const float vs3 = __builtin_amdgcn_fdot2(u2h(q1.w), wb,
                __builtin_amdgcn_fdot2(u2h(q1.z), wt, 0.f, false), false);
            const unsigned pk0 = h2u(__builtin_amdgcn_cvt_pkrtz(vs0, vs1));
            const unsigned pk1 = h2u(__builtin_amdgcn_cvt_pkrtz(vs2, vs3));
            *(uint2*)&btile[lane * PITCH_ + k * 32 + wv * 4] =
                make_uint2(pk0, pk1);
        }
        __syncthreads();   // btile ready (no outstanding vmem: drain is free)

        // ================= MFMA PHASE: 9 taps x 8 MFMAs =====================
#pragma unroll
        for (int k = 0; k < K2_; ++k) {
            const __fp16* ap = wAh +
                (((size_t)(k * 8 + cc) * 16 + wv * 2) * 64 + lane) * 8;
            const f16x8 af0 = *(const f16x8*)ap;
            const f16x8 af1 = *(const f16x8*)(ap + 512);
#pragma unroll
            for (int nt = 0; nt < 4; ++nt) {
                const f16x8 bv = *(const f16x8*)
                    &btile[(nt * 16 + lr) * PITCH_ + k * 32 + lg * 8];
                acc[0][nt] = __builtin_amdgcn_mfma_f32_16x16x32_f16(
                    af0, bv, acc[0][nt], 0, 0, 0);
                acc[1][nt] = __builtin_amdgcn_mfma_f32_16x16x32_f16(
                    af1, bv, acc[1][nt], 0, 0, 0);
            }
        }
        __syncthreads();   // btile consumed; next cc may overwrite
    }

    // ---- epilogue: ReLU + store (C/D: col=lane&15 -> pixel, row=lg*4+r -> oc)
    const size_t ob = (size_t)b * C_ * HW_ + (size_t)ho * W_;
#pragma unroll
    for (int mt = 0; mt < 2; ++mt) {
        const int o0 = wv * 32 + mt * 16 + lg * 4;
#pragma unroll
        for (int nt = 0; nt < 4; ++nt) {
            const int wo = nt * 16 + lr;
#pragma unroll
            for (int r = 0; r < 4; ++r)
                out[ob + (size_t)(o0 + r) * HW_ + wo] =
                    fmaxf(acc[mt][nt][r], 0.f);
        }
    }
}

extern "C" void kernel_launch(void* const* d_in, const int* in_sizes, int n_in,
                              void* d_out, int out_size, void* d_ws, size_t ws_size,
                              hipStream_t stream) {
    const float* x      = (const float*)d_in[0];
    const float* offset = (const float*)d_in[1];
    const float* weight = (const float*)d_in[2];
    float* out          = (float*)d_out;

    const size_t wA_bytes = (size_t)K2_ * C_ * C_ * 2;        // 1.18 MB
    const size_t xq_off   = wA_bytes;                         // 16B-aligned
    const size_t ncell    = (size_t)B_ * (C_ / 2) * HW_;      // 4.19M cells
    const size_t need     = xq_off + ncell * 16;              // ~68.3 MB

    unsigned short* wAp = (unsigned short*)d_ws;
    uint4*          xqp = (uint4*)((char*)d_ws + xq_off);

    wpack_kernel<<<(C_ * C_ * K2_ + 255) / 256, 256, 0, stream>>>(weight, wAp);

    if (ws_size >= need) {
        xq2pack_kernel<<<(int)(ncell / 4 / 256), 256, 0, stream>>>(x, xqp);
        deform_main<0><<<512, 512, 0, stream>>>(x, xqp, offset, wAp, out);
    } else {
        deform_main<1><<<512, 512, 0, stream>>>(x, xqp, offset, wAp, out);
    }
}

// Round 9
// 110.520 us; speedup vs baseline: 6.6725x; 1.0886x over previous
//
#include <hip/hip_runtime.h>

// Deformable Conv2D (B=8, C=256, H=W=64, K=3, s=1, p=1) + ReLU via fp16 MFMA.
//
// Round 8: cross-phase pipelining with FIFO-legal vmcnt ordering.
//  - taps 0-4 gathers for cc+1 issued at END of MFMA phase (after all A
//    issues) -> consumed next stage phase with counted vmcnt, no drains
//  - A-fragments double-buffered in regs: af(k+1) issued during MFMA(k),
//    af(0) issued at stage-phase end
//  - btile back to per-tap [9][64][32] + round-6 swizzle (5.9M -> ~1.2M)
//  - raw lgkmcnt(0)+s_barrier at phase bounds: globals stay in flight

#define B_   8
#define C_   256
#define H_   64
#define W_   64
#define K2_  9
#define HW_  4096

typedef __fp16 f16x2 __attribute__((ext_vector_type(2)));
typedef __fp16 f16x8 __attribute__((ext_vector_type(8)));
typedef float  f32x4 __attribute__((ext_vector_type(4)));

static __device__ __forceinline__ f16x2 u2h(unsigned u) {
    union { unsigned u; f16x2 h; } v; v.u = u; return v.h;
}
static __device__ __forceinline__ unsigned h2u(f16x2 h) {
    union { unsigned u; f16x2 h; } v; v.h = h; return v.u;
}

// ---- weights -> fp16, MFMA A-fragment lane order (validated r6/r7) ----
__global__ __launch_bounds__(256) void wpack_kernel(
    const float* __restrict__ w, unsigned short* __restrict__ wA) {
    const int t = blockIdx.x * 256 + threadIdx.x;
    if (t >= C_ * C_ * K2_) return;
    const int k = t % 9;
    const int c = (t / 9) & 255;
    const int o = t / (9 * 256);
    const int cc = c >> 5, lg = (c >> 3) & 3, e = c & 7;
    const int t16 = o >> 4, lr = o & 15;
    const int dst = e + 8 * (lr + 16 * (lg + 4 * (t16 + 16 * (cc + 8 * k))));
    const __fp16 h = (__fp16)w[t];
    unsigned short us;
    __builtin_memcpy(&us, &h, 2);
    wA[dst] = us;
}

// ---- x -> fp16 2x2 quads, channel-paired 16B cells (validated r6/r7) ----
__global__ __launch_bounds__(256) void xq2pack_kernel(
    const float* __restrict__ x, uint4* __restrict__ xq2) {
    const int t = blockIdx.x * 256 + threadIdx.x;     // B*C/2*1024 threads
    const int pix4 = (t & 1023) * 4;
    const int gc2  = t >> 10;
    const int y  = pix4 >> 6;
    const int x0 = pix4 & 63;
    const int rb = (y == 63) ? 0 : W_;
    const int nx = (x0 == 60) ? 3 : 4;
    const float* p0 = x + (size_t)(2 * gc2) * HW_ + pix4;
    const float* p1 = p0 + HW_;
    const float4 A0 = *(const float4*)p0;        const float nA0 = p0[nx];
    const float4 B0 = *(const float4*)(p0 + rb); const float nB0 = p0[rb + nx];
    const float4 A1 = *(const float4*)p1;        const float nA1 = p1[nx];
    const float4 B1 = *(const float4*)(p1 + rb); const float nB1 = p1[rb + nx];
    const float a0[5] = {A0.x, A0.y, A0.z, A0.w, nA0};
    const float b0[5] = {B0.x, B0.y, B0.z, B0.w, nB0};
    const float a1[5] = {A1.x, A1.y, A1.z, A1.w, nA1};
    const float b1[5] = {B1.x, B1.y, B1.z, B1.w, nB1};
    uint4* dst = xq2 + (size_t)gc2 * HW_ + pix4;
#pragma unroll
    for (int i = 0; i < 4; ++i) {
        uint4 cell;
        cell.x = h2u(__builtin_amdgcn_cvt_pkrtz(a0[i], a0[i + 1]));
        cell.y = h2u(__builtin_amdgcn_cvt_pkrtz(b0[i], b0[i + 1]));
        cell.z = h2u(__builtin_amdgcn_cvt_pkrtz(a1[i], a1[i + 1]));
        cell.w = h2u(__builtin_amdgcn_cvt_pkrtz(b1[i], b1[i + 1]));
        dst[i] = cell;
    }
}

// MODE 0: pipelined 16B cell gathers. MODE 1: f32 corner loads (fallback).
template<int MODE>
__global__ __launch_bounds__(512, 4) void deform_main(
    const float* __restrict__ x, const uint4* __restrict__ xq2,
    const float* __restrict__ offset, const unsigned short* __restrict__ wA,
    float* __restrict__ out)
{
    const int bid = blockIdx.x;
    const int b = bid & 7, ho = bid >> 3;     // batch -> XCD
    const int tid = threadIdx.x;
    const int lane = tid & 63;                // staging pixel; MFMA lane
    const int wv   = tid >> 6;                // wave 0..7
    const int lr = lane & 15, lg = (lane >> 4) & 3;

    __shared__ int   gaddr[K2_][W_];          // quad base ys*64+xs
    __shared__ uint2 gw2[K2_][W_];            // fp16 pairs (w00,w01),(w10,w11)
    __shared__ alignas(16) unsigned short btile[K2_][W_][32];   // 36 KB

    // ---- geometry: 9 taps x 64 pixels (validated r4-r7) ----
    for (int e = tid; e < K2_ * W_; e += 512) {
        const int k = e >> 6, wo = e & 63;
        const float offy = offset[((b * 18 + 2 * k    ) * H_ + ho) * W_ + wo];
        const float offx = offset[((b * 18 + 2 * k + 1) * H_ + ho) * W_ + wo];
        const float py = (float)(k / 3 + ho - 1) + offy;
        const float px = (float)(k % 3 + wo - 1) + offx;
        const float y0f = floorf(py), x0f = floorf(px);
        const int   y0 = (int)y0f,   x0 = (int)x0f;
        const float fy = py - y0f,   fx = px - x0f;
        const float wy0 = (y0 >= 0  && y0 < H_)     ? 1.f - fy : 0.f;
        const float wy1 = (y0 >= -1 && y0 < H_ - 1) ? fy       : 0.f;
        const float wx0 = (x0 >= 0  && x0 < W_)     ? 1.f - fx : 0.f;
        const float wx1 = (x0 >= -1 && x0 < W_ - 1) ? fx       : 0.f;
        const int ys = min(max(y0, 0), H_ - 2);
        const int xs = min(max(x0, 0), W_ - 2);
        const float qy0 = (ys == y0 ? wy0 : 0.f) + (ys == y0 + 1 ? wy1 : 0.f);
        const float qy1 = (ys + 1 == y0 ? wy0 : 0.f) + (ys + 1 == y0 + 1 ? wy1 : 0.f);
        const float qx0 = (xs == x0 ? wx0 : 0.f) + (xs == x0 + 1 ? wx1 : 0.f);
        const float qx1 = (xs + 1 == x0 ? wx0 : 0.f) + (xs + 1 == x0 + 1 ? wx1 : 0.f);
        gaddr[k][wo] = ys * W_ + xs;
        gw2[k][wo] = make_uint2(
            h2u(__builtin_amdgcn_cvt_pkrtz(qy0 * qx0, qy0 * qx1)),
            h2u(__builtin_amdgcn_cvt_pkrtz(qy1 * qx0, qy1 * qx1)));
    }
    __syncthreads();

    f32x4 acc[2][4];
#pragma unroll
    for (int m = 0; m < 2; ++m)
#pragma unroll
        for (int n = 0; n < 4; ++n) acc[m][n] = (f32x4)0.f;

    const __fp16* wAh = (const __fp16*)wA;

    if constexpr (MODE == 0) {
        // wave wv: channels cc*32 + wv*4 .. +3 -> cell planes cc*16 + wv*2 + {0,1}
        const uint4* xqb = xq2 + ((size_t)(b * (C_ / 2)) + wv * 2) * HW_;
        const uint4* pS  = xqb;                   // planes of cc being staged

        uint4 qa[5], qb[5];                       // depth-5 gather rotation
        f16x8 afr0[2], afr1[2];                   // A double-buffer (k parity)

        // prologue: taps 0-4 gathers for cc=0
#pragma unroll
        for (int j = 0; j < 5; ++j) {
            const int a = gaddr[j][lane];
            qa[j] = pS[a];
            qb[j] = pS[HW_ + a];
        }

        for (int cc = 0; cc < 8; ++cc) {
            // ============ STAGE PHASE ============
#pragma unroll
            for (int k = 0; k < K2_; ++k) {
                const uint4 q0 = qa[k % 5];       // counted vmcnt wait
                const uint4 q1 = qb[k % 5];
                if (k < 4) {                      // refill slot k for tap k+5
                    const int a = gaddr[k + 5][lane];
                    qa[k] = pS[a];
                    qb[k] = pS[HW_ + a];
                }
                const uint2 wp = gw2[k][lane];
                const f16x2 wt = u2h(wp.x), wb = u2h(wp.y);
                const float vs0 = __builtin_amdgcn_fdot2(u2h(q0.y), wb,
                    __builtin_amdgcn_fdot2(u2h(q0.x), wt, 0.f, false), false);
                const float vs1 = __builtin_amdgcn_fdot2(u2h(q0.w), wb,
                    __builtin_amdgcn_fdot2(u2h(q0.z), wt, 0.f, false), false);
                const float vs2 = __builtin_amdgcn_fdot2(u2h(q1.y), wb,
                    __builtin_amdgcn_fdot2(u2h(q1.x), wt, 0.f, false), false);
                const float vs3 = __builtin_amdgcn_fdot2(u2h(q1.w), wb,
                    __builtin_amdgcn_fdot2(u2h(q1.z), wt, 0.f, false), false);
                const unsigned pk0 = h2u(__builtin_amdgcn_cvt_pkrtz(vs0, vs1));
                const unsigned pk1 = h2u(__builtin_amdgcn_cvt_pkrtz(vs2, vs3));
                const int slot = wv ^ (((lane >> 1) & 3) << 1);
                *(uint2*)&btile[k][lane][slot * 4] = make_uint2(pk0, pk1);
                if (k == 8) {                     // issue af(k=0) for MFMA phase
                    const __fp16* ap0 = wAh +
                        (((size_t)(cc) * 16 + wv * 2) * 64 + lane) * 8;
                    afr0[0] = *(const f16x8*)ap0;
                    afr0[1] = *(const f16x8*)(ap0 + 512);
                }
            }
            asm volatile("s_waitcnt lgkmcnt(0)" ::: "memory");
            __builtin_amdgcn_s_barrier();

            // ============ MFMA PHASE ============
#pragma unroll
            for (int k = 0; k < K2_; ++k) {
                if (k < 8) {                      // issue af(k+1)
                    const __fp16* apn = wAh +
                        (((size_t)((k + 1) * 8 + cc) * 16 + wv * 2) * 64 + lane) * 8;
                    if ((k & 1) == 0) {
                        afr1[0] = *(const f16x8*)apn;
                        afr1[1] = *(const f16x8*)(apn + 512);
                    } else {
                        afr0[0] = *(const f16x8*)apn;
                        afr0[1] = *(const f16x8*)(apn + 512);
                    }
                }
                if (k == 8 && cc < 7) {           // hoist next-cc taps 0-4 gathers
                    pS = xqb + (size_t)(cc + 1) * 16 * HW_;
#pragma unroll
                    for (int j = 0; j < 5; ++j) {
                        const int a = gaddr[j][lane];
                        qa[j] = pS[a];
                        qb[j] = pS[HW_ + a];
                    }
                }
                const f16x8 a0 = (k & 1) ? afr1[0] : afr0[0];
                const f16x8 a1 = (k & 1) ? afr1[1] : afr0[1];
#pragma unroll
                for (int nt = 0; nt < 4; ++nt) {
                    const int prow = nt * 16 + lr;
                    const int rs = (2 * lg) ^ (((prow >> 1) & 3) << 1);
                    const f16x8 bv = *(const f16x8*)&btile[k][prow][rs * 4];
                    acc[0][nt] = __builtin_amdgcn_mfma_f32_16x16x32_f16(
                        a0, bv, acc[0][nt], 0, 0, 0);
                    acc[1][nt] = __builtin_amdgcn_mfma_f32_16x16x32_f16(
                        a1, bv, acc[1][nt], 0, 0, 0);
                }
            }
            asm volatile("s_waitcnt lgkmcnt(0)" ::: "memory");
            __builtin_amdgcn_s_barrier();
        }
    } else {
        // fallback: direct f32 corner loads, plain __syncthreads structure
        const float* xfb = x + ((size_t)(b * C_) + wv * 4) * HW_;
        for (int cc = 0; cc < 8; ++cc) {
#pragma unroll
            for (int k = 0; k < K2_; ++k) {
                const int a = gaddr[k][lane];
                const uint2 wp = gw2[k][lane];
                const f16x2 wt = u2h(wp.x), wb = u2h(wp.y);
                const float w00 = (float)wt.x, w01 = (float)wt.y;
                const float w10 = (float)wb.x, w11 = (float)wb.y;
                float vs[4];
#pragma unroll
                for (int j = 0; j < 4; ++j) {
                    const float* pl = xfb + (size_t)(cc * 32 + j) * HW_;
                    vs[j] = w00 * pl[a] + w01 * pl[a + 1]
                          + w10 * pl[a + W_] + w11 * pl[a + W_ + 1];
                }
                const unsigned pk0 = h2u(__builtin_amdgcn_cvt_pkrtz(vs[0], vs[1]));
                const unsigned pk1 = h2u(__builtin_amdgcn_cvt_pkrtz(vs[2], vs[3]));
                const int slot = wv ^ (((lane >> 1) & 3) << 1);
                *(uint2*)&btile[k][lane][slot * 4] = make_uint2(pk0, pk1);
            }
            __syncthreads();
#pragma unroll
            for (int k = 0; k < K2_; ++k) {
                const __fp16* ap = wAh +
                    (((size_t)(k * 8 + cc) * 16 + wv * 2) * 64 + lane) * 8;
                const f16x8 a0 = *(const f16x8*)ap;
                const f16x8 a1 = *(const f16x8*)(ap + 512);
#pragma unroll
                for (int nt = 0; nt < 4; ++nt) {
                    const int prow = nt * 16 + lr;
                    const int rs = (2 * lg) ^ (((prow >> 1) & 3) << 1);
                    const f16x8 bv = *(const f16x8*)&btile[k][prow][rs * 4];
                    acc[0][nt] = __builtin_amdgcn_mfma_f32_16x16x32_f16(
                        a0, bv, acc[0][nt], 0, 0, 0);
                    acc[1][nt] = __builtin_amdgcn_mfma_f32_16x16x32_f16(
                        a1, bv, acc[1][nt], 0, 0, 0);
                }
            }
            __syncthreads();
        }
    }

    // ---- epilogue: ReLU + store (C/D: col=lane&15 -> pixel, row=lg*4+r -> oc)
    const size_t ob = (size_t)b * C_ * HW_ + (size_t)ho * W_;
#pragma unroll
    for (int mt = 0; mt < 2; ++mt) {
        const int o0 = wv * 32 + mt * 16 + lg * 4;
#pragma unroll
        for (int nt = 0; nt < 4; ++nt) {
            const int wo = nt * 16 + lr;
#pragma unroll
            for (int r = 0; r < 4; ++r)
                out[ob + (size_t)(o0 + r) * HW_ + wo] =
                    fmaxf(acc[mt][nt][r], 0.f);
        }
    }
}

extern "C" void kernel_launch(void* const* d_in, const int* in_sizes, int n_in,
                              void* d_out, int out_size, void* d_ws, size_t ws_size,
                              hipStream_t stream) {
    const float* x      = (const float*)d_in[0];
    const float* offset = (const float*)d_in[1];
    const float* weight = (const float*)d_in[2];
    float* out          = (float*)d_out;

    const size_t wA_bytes = (size_t)K2_ * C_ * C_ * 2;        // 1.18 MB
    const size_t xq_off   = wA_bytes;                         // 16B-aligned
    const size_t ncell    = (size_t)B_ * (C_ / 2) * HW_;      // 4.19M cells
    const size_t need     = xq_off + ncell * 16;              // ~68.3 MB

    unsigned short* wAp = (unsigned short*)d_ws;
    uint4*          xqp = (uint4*)((char*)d_ws + xq_off);

    wpack_kernel<<<(C_ * C_ * K2_ + 255) / 256, 256, 0, stream>>>(weight, wAp);

    if (ws_size >= need) {
        xq2pack_kernel<<<(int)(ncell / 4 / 256), 256, 0, stream>>>(x, xqp);
        deform_main<0><<<512, 512, 0, stream>>>(x, xqp, offset, wAp, out);
    } else {
        deform_main<1><<<512, 512, 0, stream>>>(x, xqp, offset, wAp, out);
    }
}